// Round 4
// baseline (1285.753 us; speedup 1.0000x reference)
//
#include <hip/hip_runtime.h>
#include <hip/hip_bf16.h>
#include <stdint.h>

#define B_ 4
#define N_ 8192
#define D_ 128
#define E_ 262144

typedef __bf16 bf16x8 __attribute__((ext_vector_type(8)));
typedef unsigned short u16x8 __attribute__((ext_vector_type(8)));
typedef float f32x4 __attribute__((ext_vector_type(4)));

constexpr int HASH_LOG = 20;
constexpr unsigned HASH_SIZE = 1u << HASH_LOG;
constexpr unsigned HASH_MASK = HASH_SIZE - 1u;
constexpr int BUCKET_CAP = 128;   // Poisson(32) per src; P(>=128) ~ 1e-44 — safe

// ws layout (bytes):
constexpr size_t OFF_HB     = 0;         // bf16 h [B][N][D]          8,388,608
constexpr size_t OFF_W1T    = 8388608;   // bf16 W1^T [128][256]         65,536
constexpr size_t OFF_HASH   = 8454144;   // u64 hash [1<<20]          8,388,608
constexpr size_t OFF_SCORES = 16842752;  // float4 scores [E]         4,194,304
constexpr size_t OFF_CNT    = 21037056;  // int cnt [N]                  32,768
constexpr size_t OFF_BUCKET = 21069824;  // int bucket [N][128]       4,194,304

__device__ __forceinline__ unsigned short f2bf(float f) {
  union { float f; unsigned u; } v; v.f = f;
  unsigned r = v.u + 0x7fffu + ((v.u >> 16) & 1u);  // RNE
  return (unsigned short)(r >> 16);
}

__global__ void cast_h_k(const float* __restrict__ h, unsigned short* __restrict__ o) {
  int i = blockIdx.x * blockDim.x + threadIdx.x;   // 1,048,576 threads x 4 elems
  float4 v = reinterpret_cast<const float4*>(h)[i];
  ushort4 r;
  r.x = f2bf(v.x); r.y = f2bf(v.y); r.z = f2bf(v.z); r.w = f2bf(v.w);
  reinterpret_cast<ushort4*>(o)[i] = r;
}

__global__ void tw1_k(const float* __restrict__ W1, unsigned short* __restrict__ o) {
  int i = blockIdx.x * blockDim.x + threadIdx.x;   // 32768: i = d*256 + k
  int d = i >> 8, k = i & 255;
  o[i] = f2bf(W1[k * 128 + d]);
}

__global__ void hash_insert_k(const int* __restrict__ ei,
                              unsigned long long* __restrict__ tab) {
  int e = blockIdx.x * blockDim.x + threadIdx.x;
  unsigned s = (unsigned)ei[e];
  unsigned d = (unsigned)ei[E_ + e];
  unsigned key = s * (unsigned)N_ + d;             // < 2^26
  unsigned long long pack = (((unsigned long long)(key + 1u)) << 32) | (unsigned long long)(unsigned)e;
  unsigned slot = (key * 2654435761u) & HASH_MASK;
  for (;;) {
    unsigned long long cur = tab[slot];
    if (cur == 0ull) {
      unsigned long long prev = atomicCAS(&tab[slot], 0ull, pack);
      if (prev == 0ull) return;
      cur = prev;
    }
    if ((cur >> 32) == (unsigned long long)(key + 1u)) {
      atomicMax(&tab[slot], pack);                 // same key: max edge id wins
      return;
    }
    slot = (slot + 1u) & HASH_MASK;
  }
}

// winner (max-e per (src,dst)) -> append into per-src bucket
__global__ void winner_place_k(const int* __restrict__ ei,
                               const unsigned long long* __restrict__ tab,
                               int* __restrict__ cnt, int* __restrict__ bucket) {
  int e = blockIdx.x * blockDim.x + threadIdx.x;
  unsigned s = (unsigned)ei[e];
  unsigned d = (unsigned)ei[E_ + e];
  unsigned key = s * (unsigned)N_ + d;
  unsigned slot = (key * 2654435761u) & HASH_MASK;
  for (;;) {
    unsigned long long cur = tab[slot];
    if ((cur >> 32) == (unsigned long long)(key + 1u)) {
      if ((unsigned)(cur & 0xffffffffull) == (unsigned)e) {
        int pos = atomicAdd(&cnt[s], 1);
        if (pos < BUCKET_CAP) bucket[s * BUCKET_CAP + pos] = e;
      }
      return;
    }
    slot = (slot + 1u) & HASH_MASK;
  }
}

// 64 edges/block: M = 256 rows (row = e_local*4 + b), K = 256, N = 128.
// 8 waves of 512 threads; wave w owns rows [w*32, w*32+32).
__global__ __launch_bounds__(512, 4) void edge_mlp_k(
    const int* __restrict__ ei,
    const unsigned short* __restrict__ hb,    // bf16 bits [B][N][D]
    const unsigned short* __restrict__ w1t,   // bf16 bits [128][256]
    const float* __restrict__ b1,
    const float* __restrict__ w2,
    const float* __restrict__ b2,
    float4* __restrict__ scores) {            // [E] = {b0,b1,b2,b3}
  __shared__ char lds[65536];                 // W1^T, XOR-swizzled rows of 512 B
  const int tid  = threadIdx.x;
  const int lane = tid & 63;
  const int wid  = tid >> 6;                  // 0..7
  const int l15  = lane & 15;
  const int lg   = lane >> 4;

  // stage W1^T -> LDS with byte ^= ((row&7)<<4) swizzle
  {
    const uint4* g = reinterpret_cast<const uint4*>(w1t);
    #pragma unroll
    for (int it = 0; it < 8; ++it) {
      int i = it * 512 + tid;                 // uint4 index, 4096 total
      uint4 v = g[i];
      int byte = i * 16;
      int dd = byte >> 9;
      int within = byte & 511;
      *reinterpret_cast<uint4*>(&lds[dd * 512 + (within ^ ((dd & 7) << 4))]) = v;
    }
  }

  const int e0 = blockIdx.x * 64;

  unsigned offS[2], offD[2];
  #pragma unroll
  for (int m = 0; m < 2; ++m) {
    int row = wid * 32 + m * 16 + l15;
    int e = e0 + (row >> 2);
    int b = row & 3;
    offS[m] = ((unsigned)b * N_ + (unsigned)ei[e]) * D_;
    offD[m] = ((unsigned)b * N_ + (unsigned)ei[E_ + e]) * D_;
  }

  __syncthreads();

  f32x4 acc[2][8];
  #pragma unroll
  for (int m = 0; m < 2; ++m)
    #pragma unroll
    for (int n = 0; n < 8; ++n)
      acc[m][n] = (f32x4){0.f, 0.f, 0.f, 0.f};

  const int kg = 8 * lg;

  #pragma unroll
  for (int ks = 0; ks < 8; ++ks) {
    bf16x8 a[2];
    const int kin = (ks & 3) * 32 + kg;
    #pragma unroll
    for (int m = 0; m < 2; ++m) {
      unsigned off = (ks < 4 ? offS[m] : offD[m]) + (unsigned)kin;
      u16x8 u = *reinterpret_cast<const u16x8*>(hb + off);
      a[m] = __builtin_bit_cast(bf16x8, u);
    }
    const int kb = ks * 64 + 16 * lg;
    #pragma unroll
    for (int n = 0; n < 8; ++n) {
      int dd = n * 16 + l15;
      uint4 v = *reinterpret_cast<const uint4*>(&lds[dd * 512 + (kb ^ ((dd & 7) << 4))]);
      bf16x8 bfr = __builtin_bit_cast(bf16x8, v);
      acc[0][n] = __builtin_amdgcn_mfma_f32_16x16x32_bf16(a[0], bfr, acc[0][n], 0, 0, 0);
      acc[1][n] = __builtin_amdgcn_mfma_f32_16x16x32_bf16(a[1], bfr, acc[1][n], 0, 0, 0);
    }
  }

  // epilogue: bias + SiLU + dot with W2, butterfly-reduce over the 128 cols
  float b1v[8], w2v[8];
  #pragma unroll
  for (int n = 0; n < 8; ++n) {
    int col = n * 16 + l15;
    b1v[n] = b1[col];
    w2v[n] = w2[col];
  }
  float sc[2][4];
  #pragma unroll
  for (int m = 0; m < 2; ++m)
    #pragma unroll
    for (int i = 0; i < 4; ++i) sc[m][i] = 0.f;
  #pragma unroll
  for (int n = 0; n < 8; ++n)
    #pragma unroll
    for (int m = 0; m < 2; ++m)
      #pragma unroll
      for (int i = 0; i < 4; ++i) {
        float v = acc[m][n][i] + b1v[n];
        float sv = v / (1.f + __expf(-v));    // SiLU
        sc[m][i] += sv * w2v[n];
      }
  #pragma unroll
  for (int m = 0; m < 2; ++m)
    #pragma unroll
    for (int i = 0; i < 4; ++i) {
      float v = sc[m][i];
      v += __shfl_xor(v, 1, 64);
      v += __shfl_xor(v, 2, 64);
      v += __shfl_xor(v, 4, 64);
      v += __shfl_xor(v, 8, 64);
      sc[m][i] = v;
    }
  const float b2v = b2[0];
  if (l15 == 0) {
    // lane's 4 acc regs = rows base..base+3 = the 4 batches of edge base>>2
    #pragma unroll
    for (int m = 0; m < 2; ++m) {
      int base = wid * 32 + m * 16 + 4 * lg;
      scores[e0 + (base >> 2)] =
          make_float4(sc[m][0] + b2v, sc[m][1] + b2v, sc[m][2] + b2v, sc[m][3] + b2v);
    }
  }
}

// One block per src row: stream zeros for all 4 batches + merge scores.
// Chunk ownership: float4-chunk c (= dst>>2) is written ONLY by thread c%256,
// so zero->score stores to the same address are same-thread program-ordered.
__global__ __launch_bounds__(256, 8) void out_writer_k(
    const int* __restrict__ ei,
    const int* __restrict__ cnt,
    const int* __restrict__ bucket,
    const float4* __restrict__ scores,
    float* __restrict__ out) {
  __shared__ int   dst_l[BUCKET_CAP];
  __shared__ float sc_l[BUCKET_CAP][4];
  const int t = threadIdx.x;
  const int src = blockIdx.x;
  int n = cnt[src];
  n = n < BUCKET_CAP ? n : BUCKET_CAP;
  if (t < n) {
    int e = bucket[src * BUCKET_CAP + t];
    dst_l[t] = ei[E_ + e];
    float4 s = scores[e];
    sc_l[t][0] = s.x; sc_l[t][1] = s.y; sc_l[t][2] = s.z; sc_l[t][3] = s.w;
  }
  __syncthreads();

  const float4 z = {0.f, 0.f, 0.f, 0.f};
  const size_t rowbase = (size_t)src * N_;
  #pragma unroll
  for (int b = 0; b < 4; ++b) {
    float* rp = out + (size_t)b * ((size_t)N_ * N_) + rowbase;
    float4* po = reinterpret_cast<float4*>(rp);
    #pragma unroll
    for (int k = 0; k < 8; ++k)
      po[t + 256 * k] = z;                    // 2048 float4 = 8192 floats
    for (int j = 0; j < n; ++j) {             // LDS broadcast scan
      int dst = dst_l[j];
      if (((dst >> 2) & 255) == t)
        rp[dst] = sc_l[j][b];
    }
  }
}

extern "C" void kernel_launch(void* const* d_in, const int* in_sizes, int n_in,
                              void* d_out, int out_size, void* d_ws, size_t ws_size,
                              hipStream_t stream) {
  const float* h  = (const float*)d_in[0];
  const int*   ei = (const int*)d_in[1];     // harness stores integer inputs as int32
  const float* W1 = (const float*)d_in[2];
  const float* b1 = (const float*)d_in[3];
  const float* W2 = (const float*)d_in[4];
  const float* b2 = (const float*)d_in[5];
  float* out = (float*)d_out;
  char*  ws  = (char*)d_ws;

  unsigned short*     hb     = (unsigned short*)(ws + OFF_HB);
  unsigned short*     w1t    = (unsigned short*)(ws + OFF_W1T);
  unsigned long long* tab    = (unsigned long long*)(ws + OFF_HASH);
  float4*             scores = (float4*)(ws + OFF_SCORES);
  int*                cnt    = (int*)(ws + OFF_CNT);
  int*                bucket = (int*)(ws + OFF_BUCKET);

  (void)hipMemsetAsync(tab, 0, (size_t)HASH_SIZE * 8, stream);
  (void)hipMemsetAsync(cnt, 0, (size_t)N_ * 4, stream);

  cast_h_k<<<4096, 256, 0, stream>>>(h, hb);
  tw1_k<<<128, 256, 0, stream>>>(W1, w1t);
  hash_insert_k<<<E_ / 256, 256, 0, stream>>>(ei, tab);
  winner_place_k<<<E_ / 256, 256, 0, stream>>>(ei, tab, cnt, bucket);
  edge_mlp_k<<<E_ / 64, 512, 0, stream>>>(ei, hb, w1t, b1, W2, b2, scores);
  out_writer_k<<<N_, 256, 0, stream>>>(ei, cnt, bucket, scores, out);
}